// Round 4
// baseline (182602.905 us; speedup 1.0000x reference)
//
#include <hip/hip_runtime.h>
#include <math.h>

namespace {

constexpr int cH  = 1024;
constexpr int cZ  = 256;
constexpr int cB  = 64;
constexpr int cT  = 256;
constexpr int cR  = 389;
constexpr int cSC = 89;
constexpr int cPF = 300;
constexpr int cIN0 = 645;              // PERF + SCORE + Z
constexpr int ISTR = 672;              // padded layer-0 input stride (floats): 168 f4, /8 segs = 21
constexpr int WSTR = 416;              // padded encoder w_ih stride (floats): 104 f4, /4 segs = 26
constexpr int XSTR = 68;               // xs_t LDS row stride (floats) -> f4 stride 17
constexpr float INV_S = 0.9999950000374997f;  // 1/sqrt(1+1e-5)
constexpr unsigned NBLK = 256;         // persistent grid (1 block/CU guaranteed by LDS+VGPR)

__device__ __forceinline__ void fma4(float4& a, const float4 x, const float4 w){
  a.x = fmaf(x.x, w.x, a.x);
  a.y = fmaf(x.y, w.y, a.y);
  a.z = fmaf(x.z, w.z, a.z);
  a.w = fmaf(x.w, w.w, a.w);
}
#define FMA4S(A, V, S) { (A).x = fmaf((V).x,(S),(A).x); (A).y = fmaf((V).y,(S),(A).y); \
                         (A).z = fmaf((V).z,(S),(A).z); (A).w = fmaf((V).w,(S),(A).w); }
__device__ __forceinline__ float fold4(const float4 a){ return (a.x + a.y) + (a.z + a.w); }
__device__ __forceinline__ float4 z4(){ return make_float4(0.f, 0.f, 0.f, 0.f); }
__device__ __forceinline__ float sigm(float x){ return 1.f / (1.f + expf(-x)); }

// device-scope sense-counting grid barrier (256 blocks, 1/CU resident by construction)
__device__ __forceinline__ void gbar(unsigned* cnt, unsigned* gen, unsigned nb){
  __syncthreads();
  if (threadIdx.x == 0){
    __threadfence();
    unsigned g = __hip_atomic_load(gen, __ATOMIC_RELAXED, __HIP_MEMORY_SCOPE_AGENT);
    unsigned a = __hip_atomic_fetch_add(cnt, 1u, __ATOMIC_ACQ_REL, __HIP_MEMORY_SCOPE_AGENT);
    if (a == nb - 1u){
      __hip_atomic_store(cnt, 0u, __ATOMIC_RELAXED, __HIP_MEMORY_SCOPE_AGENT);
      __hip_atomic_store(gen, g + 1u, __ATOMIC_RELEASE, __HIP_MEMORY_SCOPE_AGENT);
    } else {
      while (__hip_atomic_load(gen, __ATOMIC_RELAXED, __HIP_MEMORY_SCOPE_AGENT) == g)
        __builtin_amdgcn_s_sleep(2);
    }
    __threadfence();
  }
  __syncthreads();
}

// 3 weight streams x 4 activation rows, over-dims accumulate, chunk-4 batched loads.
__device__ __forceinline__ void dot3acc(
    const float4* __restrict__ w0, const float4* __restrict__ w1,
    const float4* __restrict__ w2,
    const float4* __restrict__ a0, const float4* __restrict__ a1,
    const float4* __restrict__ a2, const float4* __restrict__ a3,
    int d0, int n,
    float4 (&A0)[4], float4 (&A1)[4], float4 (&A2)[4])
{
  int d = d0;
  const int de = d0 + n;
  for (; d + 4 <= de; d += 4){
    float4 tw0[4], tw1[4], tw2[4], ta0[4], ta1[4], ta2[4], ta3[4];
    #pragma unroll
    for (int u = 0; u < 4; ++u){ tw0[u] = w0[d+u]; tw1[u] = w1[d+u]; tw2[u] = w2[d+u]; }
    #pragma unroll
    for (int u = 0; u < 4; ++u){ ta0[u] = a0[d+u]; ta1[u] = a1[d+u]; ta2[u] = a2[d+u]; ta3[u] = a3[d+u]; }
    #pragma unroll
    for (int u = 0; u < 4; ++u){
      fma4(A0[0], ta0[u], tw0[u]); fma4(A0[1], ta1[u], tw0[u]);
      fma4(A0[2], ta2[u], tw0[u]); fma4(A0[3], ta3[u], tw0[u]);
      fma4(A1[0], ta0[u], tw1[u]); fma4(A1[1], ta1[u], tw1[u]);
      fma4(A1[2], ta2[u], tw1[u]); fma4(A1[3], ta3[u], tw1[u]);
      fma4(A2[0], ta0[u], tw2[u]); fma4(A2[1], ta1[u], tw2[u]);
      fma4(A2[2], ta2[u], tw2[u]); fma4(A2[3], ta3[u], tw2[u]);
    }
  }
  for (; d < de; ++d){
    const float4 u0 = w0[d], u1 = w1[d], u2 = w2[d];
    const float4 t0 = a0[d], t1 = a1[d], t2 = a2[d], t3 = a3[d];
    fma4(A0[0], t0, u0); fma4(A0[1], t1, u0); fma4(A0[2], t2, u0); fma4(A0[3], t3, u0);
    fma4(A1[0], t0, u1); fma4(A1[1], t1, u1); fma4(A1[2], t2, u1); fma4(A1[3], t3, u1);
    fma4(A2[0], t0, u2); fma4(A2[1], t1, u2); fma4(A2[2], t2, u2); fma4(A2[3], t3, u2);
  }
}

// ---------------------------------------------------------------- init / prep
__global__ __launch_bounds__(256) void init_kernel(float* hf0, float* hb0, float* dout_tail,
                                                   unsigned* bar){
  const int idx = blockIdx.x * 256 + threadIdx.x;
  const int stride = gridDim.x * 256;
  for (int i = idx; i < cB * cH; i += stride){ hf0[i] = 0.f; hb0[i] = 0.f; }
  for (int i = idx; i < 2 * cB * cZ; i += stride) dout_tail[i] = 0.f;
  if (idx < 64) bar[idx] = 0u;
}

__global__ __launch_bounds__(256) void pad_w0_kernel(const float* __restrict__ w,
                                                     float* __restrict__ wp){
  const int idx = blockIdx.x * 256 + threadIdx.x;
  const int stride = gridDim.x * 256;
  const int n = 3 * cH * ISTR;
  for (int i = idx; i < n; i += stride){
    const int r = i / ISTR;
    const int c = i - r * ISTR;
    wp[i] = (c < cIN0) ? w[(size_t)r * cIN0 + c] : 0.f;
  }
}

__global__ __launch_bounds__(256) void pad_wih_kernel(const float* __restrict__ w,
                                                      float* __restrict__ wp){
  const int idx = blockIdx.x * 256 + threadIdx.x;
  const int stride = gridDim.x * 256;
  const int n = 3 * cH * WSTR;
  for (int i = idx; i < n; i += stride){
    const int r = i / WSTR;
    const int c = i - r * WSTR;
    wp[i] = (c < cR) ? w[(size_t)r * cR + c] : 0.f;
  }
}

// ---------------------------------------------------------------- encoder (persistent)
// 256 blocks x 512 thr: dir = bid>>7, kblk = bid&127 (8 h-rows, all 64 batches).
// tid: seg = tid>>7 (4 d-segs); sub = tid&127: ty = sub>>4 (8 rows), tx = sub&15 (4 batches).
__global__ __launch_bounds__(512, 2) void enc_persist(
    const float* __restrict__ x,
    const float* __restrict__ wihPf, const float* __restrict__ whh_f,
    const float* __restrict__ bih_f, const float* __restrict__ bhh_f,
    const float* __restrict__ wihPb, const float* __restrict__ whh_b,
    const float* __restrict__ bih_b, const float* __restrict__ bhh_b,
    float* __restrict__ hfA, float* __restrict__ hfB,
    float* __restrict__ hbA, float* __restrict__ hbB,
    unsigned* __restrict__ cnt, unsigned* __restrict__ gen)
{
  const int bid  = blockIdx.x;
  const int dir  = bid >> 7;
  const int kblk = bid & 127;
  const int k0   = kblk * 8;

  const float* wih = dir ? wihPb : wihPf;
  const float* whh = dir ? whh_b : whh_f;
  const float* bih = dir ? bih_b : bih_f;
  const float* bhh = dir ? bhh_b : bhh_f;
  float* bufA = dir ? hbA : hfA;
  float* bufB = dir ? hbB : hfB;

  const int tid = threadIdx.x;
  const int seg = tid >> 7;          // 0..3
  const int sub = tid & 127;
  const int ty  = sub >> 4;          // 0..7 (h-row)
  const int tx  = sub & 15;          // 0..15 (4 batches)
  const int k   = k0 + ty;
  const int b0  = tx * 4;

  __shared__ alignas(16) float xs[WSTR * XSTR];   // transposed x tile [d][b], 113 KB
  __shared__ float part[4][4][8][65];             // 33.3 KB

  // zero padded d-rows (389..415) once
  for (int i = tid; i < (WSTR - cR) * XSTR; i += 512){
    const int rr = i / XSTR, cc = i - rr * XSTR;
    xs[(cR + rr) * XSTR + cc] = 0.f;
  }

  const float4* w0i = (const float4*)wih + (size_t)k * (WSTR/4);
  const float4* w1i = (const float4*)wih + (size_t)(cH + k) * (WSTR/4);
  const float4* w2i = (const float4*)wih + (size_t)(2*cH + k) * (WSTR/4);
  const float4* w0h = (const float4*)whh + (size_t)k * 256;
  const float4* w1h = (const float4*)whh + (size_t)(cH + k) * 256;
  const float4* w2h = (const float4*)whh + (size_t)(2*cH + k) * 256;

  for (int t = 0; t < cT; ++t){
    const float* hin = (t & 1) ? bufB : bufA;
    float*      hout = (t & 1) ? bufA : bufB;
    const int tt = dir ? (cT - 1 - t) : t;
    const float* xin = x + (size_t)tt * cB * cR;

    // stage x_t transposed into LDS (coalesced global reads)
    {
      const int dl = tid & 63, bg = tid >> 6;
      for (int pass = 0; pass < 8; ++pass){
        const int b = pass * 8 + bg;
        const float* xr = xin + (size_t)b * cR;
        for (int d = dl; d < cR; d += 64) xs[d * XSTR + b] = xr[d];
      }
    }
    __syncthreads();

    // phase 1: x @ w_ih^T  (over-batch accumulate, scalar-broadcast weights)
    float4 bR = z4(), bZ = z4(), bNI = z4();
    {
      const float4* xsT = (const float4*)xs;
      const int d0 = seg * 26, de = d0 + 26;
      int d = d0;
      for (; d + 4 <= de; d += 4){
        float4 tw0[4], tw1[4], tw2[4];
        #pragma unroll
        for (int u = 0; u < 4; ++u){ tw0[u] = w0i[d+u]; tw1[u] = w1i[d+u]; tw2[u] = w2i[d+u]; }
        #pragma unroll
        for (int u = 0; u < 4; ++u){
          const int di = d + u;
          const float4 t0 = xsT[di*68 +      tx];
          const float4 t1 = xsT[di*68 + 17 + tx];
          const float4 t2 = xsT[di*68 + 34 + tx];
          const float4 t3 = xsT[di*68 + 51 + tx];
          FMA4S(bR, t0, tw0[u].x); FMA4S(bZ, t0, tw1[u].x); FMA4S(bNI, t0, tw2[u].x);
          FMA4S(bR, t1, tw0[u].y); FMA4S(bZ, t1, tw1[u].y); FMA4S(bNI, t1, tw2[u].y);
          FMA4S(bR, t2, tw0[u].z); FMA4S(bZ, t2, tw1[u].z); FMA4S(bNI, t2, tw2[u].z);
          FMA4S(bR, t3, tw0[u].w); FMA4S(bZ, t3, tw1[u].w); FMA4S(bNI, t3, tw2[u].w);
        }
      }
      for (; d < de; ++d){
        const float4 u0 = w0i[d], u1 = w1i[d], u2 = w2i[d];
        const float4 t0 = xs ? ((const float4*)xs)[d*68 + tx] : z4();
        const float4 t1 = ((const float4*)xs)[d*68 + 17 + tx];
        const float4 t2 = ((const float4*)xs)[d*68 + 34 + tx];
        const float4 t3 = ((const float4*)xs)[d*68 + 51 + tx];
        FMA4S(bR, t0, u0.x); FMA4S(bZ, t0, u1.x); FMA4S(bNI, t0, u2.x);
        FMA4S(bR, t1, u0.y); FMA4S(bZ, t1, u1.y); FMA4S(bNI, t1, u2.y);
        FMA4S(bR, t2, u0.z); FMA4S(bZ, t2, u1.z); FMA4S(bNI, t2, u2.z);
        FMA4S(bR, t3, u0.w); FMA4S(bZ, t3, u1.w); FMA4S(bNI, t3, u2.w);
      }
    }

    // phase 2: h @ w_hh^T  (over-dims accumulate)
    float4 R2[4], Z2[4], NH2[4];
    #pragma unroll
    for (int j = 0; j < 4; ++j){ R2[j] = z4(); Z2[j] = z4(); NH2[j] = z4(); }
    {
      const float4* h4 = (const float4*)hin;
      dot3acc(w0h, w1h, w2h,
              h4 + (size_t)(b0+0)*256, h4 + (size_t)(b0+1)*256,
              h4 + (size_t)(b0+2)*256, h4 + (size_t)(b0+3)*256,
              seg * 64, 64, R2, Z2, NH2);
    }

    part[seg][0][ty][b0+0] = bR.x + fold4(R2[0]);
    part[seg][0][ty][b0+1] = bR.y + fold4(R2[1]);
    part[seg][0][ty][b0+2] = bR.z + fold4(R2[2]);
    part[seg][0][ty][b0+3] = bR.w + fold4(R2[3]);
    part[seg][1][ty][b0+0] = bZ.x + fold4(Z2[0]);
    part[seg][1][ty][b0+1] = bZ.y + fold4(Z2[1]);
    part[seg][1][ty][b0+2] = bZ.z + fold4(Z2[2]);
    part[seg][1][ty][b0+3] = bZ.w + fold4(Z2[3]);
    part[seg][2][ty][b0+0] = bNI.x;
    part[seg][2][ty][b0+1] = bNI.y;
    part[seg][2][ty][b0+2] = bNI.z;
    part[seg][2][ty][b0+3] = bNI.w;
    part[seg][3][ty][b0+0] = fold4(NH2[0]);
    part[seg][3][ty][b0+1] = fold4(NH2[1]);
    part[seg][3][ty][b0+2] = fold4(NH2[2]);
    part[seg][3][ty][b0+3] = fold4(NH2[3]);
    __syncthreads();
    {
      const int row = tid >> 6, bb = tid & 63;   // 8 x 64 = 512 outputs
      float rs = 0.f, zs = 0.f, nis = 0.f, nhs = 0.f;
      #pragma unroll
      for (int s = 0; s < 4; ++s){
        rs  += part[s][0][row][bb];
        zs  += part[s][1][row][bb];
        nis += part[s][2][row][bb];
        nhs += part[s][3][row][bb];
      }
      const int kk = k0 + row;
      const float r  = sigm(rs + bih[kk] + bhh[kk]);
      const float zg = sigm(zs + bih[cH + kk] + bhh[cH + kk]);
      const float nn = tanhf(nis + bih[2 * cH + kk] + r * (nhs + bhh[2 * cH + kk]));
      const float hp = hin[(size_t)bb * cH + kk];
      hout[(size_t)bb * cH + kk] = (1.f - zg) * nn + zg * hp;
    }
    gbar(cnt, gen, NBLK);
  }
}

// ---------------------------------------------------------------- decoder GRU phase
// block: 4 h-rows (k0 = bid*4), all 64 batches.
// tid: seg = tid>>6 (8 d-segs); lane: ty = (lane>>4) (h-row), tx = lane&15 (4 batches).
__device__ __forceinline__ void dec_gru_phase(
    int tid, int k0,
    const float* __restrict__ in, int Lf4,
    const float* __restrict__ hprev,
    const float* __restrict__ wih, int LwF4,
    const float* __restrict__ whh,
    const float* __restrict__ bih, const float* __restrict__ bhh,
    float* __restrict__ hout, float (&part)[8][4][4][65])
{
  const int seg = tid >> 6;
  const int lane = tid & 63;
  const int tx = lane & 15;
  const int ty = lane >> 4;
  const int k  = k0 + ty;
  const int b0 = tx * 4;

  float4 AR[4], AZ[4], ANI[4], ANH[4];
  #pragma unroll
  for (int j = 0; j < 4; ++j){ AR[j] = z4(); AZ[j] = z4(); ANI[j] = z4(); ANH[j] = z4(); }

  {
    const float4* w0 = (const float4*)wih + (size_t)k * LwF4;
    const float4* w1 = (const float4*)wih + (size_t)(cH + k) * LwF4;
    const float4* w2 = (const float4*)wih + (size_t)(2*cH + k) * LwF4;
    const float4* a  = (const float4*)in;
    const int n = Lf4 >> 3;
    dot3acc(w0, w1, w2,
            a + (size_t)(b0+0)*Lf4, a + (size_t)(b0+1)*Lf4,
            a + (size_t)(b0+2)*Lf4, a + (size_t)(b0+3)*Lf4,
            seg * n, n, AR, AZ, ANI);
  }
  {
    const float4* w0 = (const float4*)whh + (size_t)k * 256;
    const float4* w1 = (const float4*)whh + (size_t)(cH + k) * 256;
    const float4* w2 = (const float4*)whh + (size_t)(2*cH + k) * 256;
    const float4* h4 = (const float4*)hprev;
    dot3acc(w0, w1, w2,
            h4 + (size_t)(b0+0)*256, h4 + (size_t)(b0+1)*256,
            h4 + (size_t)(b0+2)*256, h4 + (size_t)(b0+3)*256,
            seg * 32, 32, AR, AZ, ANH);
  }

  #pragma unroll
  for (int j = 0; j < 4; ++j){
    part[seg][0][ty][b0+j] = fold4(AR[j]);
    part[seg][1][ty][b0+j] = fold4(AZ[j]);
    part[seg][2][ty][b0+j] = fold4(ANI[j]);
    part[seg][3][ty][b0+j] = fold4(ANH[j]);
  }
  __syncthreads();
  if (tid < 256){
    const int row = tid >> 6, bb = tid & 63;
    float rs = 0.f, zs = 0.f, nis = 0.f, nhs = 0.f;
    #pragma unroll
    for (int s = 0; s < 8; ++s){
      rs  += part[s][0][row][bb];
      zs  += part[s][1][row][bb];
      nis += part[s][2][row][bb];
      nhs += part[s][3][row][bb];
    }
    const int kk = k0 + row;
    const float r  = sigm(rs + bih[kk] + bhh[kk]);
    const float zg = sigm(zs + bih[cH + kk] + bhh[cH + kk]);
    const float nn = tanhf(nis + bih[2 * cH + kk] + r * (nhs + bhh[2 * cH + kk]));
    const float hp = hprev[(size_t)bb * cH + kk];
    hout[(size_t)bb * cH + kk] = (1.f - zg) * nn + zg * hp;
  }
}

// ---------------------------------------------------------------- decoder (persistent)
__global__ __launch_bounds__(512, 2) void dec_persist(
    const float* __restrict__ x,
    const float* __restrict__ hfA, const float* __restrict__ hbA,
    const float* __restrict__ w_mu, const float* __restrict__ b_mu,
    const float* __restrict__ w_init, const float* __restrict__ b_init,
    const float* __restrict__ wp0,   const float* __restrict__ w_hh0,
    const float* __restrict__ b_ih0, const float* __restrict__ b_hh0,
    const float* __restrict__ w_ih1, const float* __restrict__ w_hh1,
    const float* __restrict__ b_ih1, const float* __restrict__ b_hh1,
    const float* __restrict__ w_ih2, const float* __restrict__ w_hh2,
    const float* __restrict__ b_ih2, const float* __restrict__ b_hh2,
    const float* __restrict__ w_out, const float* __restrict__ b_out,
    float* __restrict__ h0A, float* __restrict__ h0B,
    float* __restrict__ h1A, float* __restrict__ h1B,
    float* __restrict__ h2A, float* __restrict__ h2B,
    float* __restrict__ inp, float* __restrict__ lgbuf, float* __restrict__ dout,
    unsigned* __restrict__ cnt, unsigned* __restrict__ gen)
{
  const int bid = blockIdx.x;
  const int tid = threadIdx.x;
  const int k0  = bid * 4;

  __shared__ float part[8][4][4][65];
  __shared__ float plg[2][4][65];
  __shared__ alignas(16) float hl[2 * cH];
  __shared__ alignas(16) float zl[cZ];
  __shared__ float lg[cPF];
  __shared__ float gmax[3], glse[3];
  __shared__ float wbest[8];
  __shared__ int   wbidx[8];
  __shared__ int   amax_s;

  // ---- prologue: latent + hinit + inp init (blocks 0..63)
  if (bid < cB){
    const int b = bid;
    if (tid < 256) ((float4*)hl)[tid] = ((const float4*)(hfA + (size_t)b * cH))[tid];
    else           ((float4*)hl)[tid] = ((const float4*)(hbA + (size_t)b * cH))[tid - 256];
    __syncthreads();
    if (tid < cZ){
      const float4* h4 = (const float4*)hl;
      const float4* wr = (const float4*)(w_mu + (size_t)tid * 2 * cH);
      float4 s4 = z4();
      #pragma unroll 4
      for (int i = 0; i < 512; ++i) fma4(s4, h4[i], wr[i]);
      zl[tid] = b_mu[tid] + fold4(s4) * INV_S;
    }
    __syncthreads();
    {
      const float4* zv = (const float4*)zl;
      for (int kk = tid; kk < cH; kk += 512){
        const float4* wr = (const float4*)(w_init + (size_t)kk * cZ);
        float4 s4 = z4();
        #pragma unroll 4
        for (int i = 0; i < 64; ++i) fma4(s4, zv[i], wr[i]);
        h0A[(size_t)b * cH + kk] = tanhf(b_init[kk] + fold4(s4));
      }
      for (int c = tid; c < ISTR; c += 512){
        float v;
        if (c < cPF)            v = (c == cPF - 1) ? 1.f : 0.f;
        else if (c < cPF + cSC) v = (c == cPF + cSC - 1) ? 1.f : 0.f;
        else if (c < cIN0)      v = zl[c - (cPF + cSC)];
        else                    v = 0.f;
        inp[(size_t)b * ISTR + c] = v;
      }
    }
  }
  gbar(cnt, gen, NBLK);

  // ---- main loop
  for (int j = 0; j < cT; ++j){
    const int par = j & 1;
    const float* h0p = par ? h0B : h0A;  float* h0n = par ? h0A : h0B;
    const float* h1p = par ? h1B : h1A;  float* h1n = par ? h1A : h1B;
    const float* h2p = par ? h2B : h2A;  float* h2n = par ? h2A : h2B;

    dec_gru_phase(tid, k0, inp, ISTR/4, h0p, wp0, ISTR/4, w_hh0, b_ih0, b_hh0, h0n, part);
    gbar(cnt, gen, NBLK);
    dec_gru_phase(tid, k0, h0n, cH/4, (j == 0 ? h0n : h1p), w_ih1, cH/4, w_hh1, b_ih1, b_hh1, h1n, part);
    gbar(cnt, gen, NBLK);
    dec_gru_phase(tid, k0, h1n, cH/4, (j == 0 ? h1n : h2p), w_ih2, cH/4, w_hh2, b_ih2, b_hh2, h2n, part);
    gbar(cnt, gen, NBLK);

    // D1: logits -> lgbuf.  150 blocks x (2 p-rows, 64 batches, 4 d-segs)
    {
      const int prow = tid >> 8;          // 0..1
      const int sg4  = (tid >> 6) & 3;    // 0..3
      const int bb   = tid & 63;
      const int p    = bid * 2 + prow;
      if (bid < 150){
        const float4* wr = (const float4*)w_out + (size_t)p * 256;
        const float4* av = (const float4*)h2n + (size_t)bb * 256;
        float4 acc = z4();
        const int d0 = sg4 * 64;
        for (int c = 0; c < 64; c += 4){
          float4 tw[4], ta[4];
          #pragma unroll
          for (int u = 0; u < 4; ++u) tw[u] = wr[d0 + c + u];
          #pragma unroll
          for (int u = 0; u < 4; ++u) ta[u] = av[d0 + c + u];
          #pragma unroll
          for (int u = 0; u < 4; ++u) fma4(acc, ta[u], tw[u]);
        }
        plg[prow][sg4][bb] = fold4(acc);
      }
      __syncthreads();
      if (bid < 150 && tid < 128){
        const int pr = tid >> 6, bb2 = tid & 63;
        const int p2 = bid * 2 + pr;
        lgbuf[(size_t)bb2 * cPF + p2] = b_out[p2] +
            plg[pr][0][bb2] + plg[pr][1][bb2] + plg[pr][2][bb2] + plg[pr][3][bb2];
      }
    }
    gbar(cnt, gen, NBLK);

    // D2: softmax + argmax + next input.  blocks 0..63
    if (bid < cB){
      const int b = bid;
      if (tid < cPF) lg[tid] = lgbuf[(size_t)b * cPF + tid];
      __syncthreads();

      const int w = tid >> 6, l = tid & 63;
      if (w < 3){
        float m = -INFINITY;
        for (int p = w * 100 + l; p < w * 100 + 100; p += 64) m = fmaxf(m, lg[p]);
        #pragma unroll
        for (int off = 32; off > 0; off >>= 1) m = fmaxf(m, __shfl_xor(m, off));
        float s = 0.f;
        for (int p = w * 100 + l; p < w * 100 + 100; p += 64) s += expf(lg[p] - m);
        #pragma unroll
        for (int off = 32; off > 0; off >>= 1) s += __shfl_xor(s, off);
        if (l == 0){ gmax[w] = m; glse[w] = logf(s); }
      }
      __syncthreads();

      float best = -INFINITY; int bidx = 0x7fffffff;
      for (int p = tid; p < cPF; p += 512){
        const int g = (p >= 200) ? 2 : ((p >= 100) ? 1 : 0);
        const float o = lg[p] - gmax[g] - glse[g];
        dout[((size_t)b * cT + j) * cPF + p] = o;
        if (o > best || (o == best && p < bidx)){ best = o; bidx = p; }
      }
      #pragma unroll
      for (int off = 32; off > 0; off >>= 1){
        const float ob = __shfl_xor(best, off);
        const int   oi = __shfl_xor(bidx, off);
        if (ob > best || (ob == best && oi < bidx)){ best = ob; bidx = oi; }
      }
      if (l == 0){ wbest[w] = best; wbidx[w] = bidx; }
      __syncthreads();
      if (tid == 0){
        float bb = wbest[0]; int bi = wbidx[0];
        #pragma unroll
        for (int q = 1; q < 8; ++q)
          if (wbest[q] > bb || (wbest[q] == bb && wbidx[q] < bi)){ bb = wbest[q]; bi = wbidx[q]; }
        amax_s = bi;
      }
      __syncthreads();

      const int am = amax_s;
      for (int p = tid; p < cPF; p += 512) inp[(size_t)b * ISTR + p] = (p == am) ? 1.f : 0.f;
      if (tid < cSC) inp[(size_t)b * ISTR + cPF + tid] = x[((size_t)j * cB + b) * cR + tid];
    }
    gbar(cnt, gen, NBLK);
  }
}

} // namespace

// ---------------------------------------------------------------- host
extern "C" void kernel_launch(void* const* d_in, const int* in_sizes, int n_in,
                              void* d_out, int out_size, void* d_ws, size_t ws_size,
                              hipStream_t stream)
{
  const float* x     = (const float*)d_in[0];
  const float* wih_f = (const float*)d_in[2];
  const float* whh_f = (const float*)d_in[3];
  const float* bih_f = (const float*)d_in[4];
  const float* bhh_f = (const float*)d_in[5];
  const float* wih_b = (const float*)d_in[6];
  const float* whh_b = (const float*)d_in[7];
  const float* bih_b = (const float*)d_in[8];
  const float* bhh_b = (const float*)d_in[9];
  const float* w_mu  = (const float*)d_in[10];
  const float* b_mu  = (const float*)d_in[11];
  const float* w_init= (const float*)d_in[14];
  const float* b_init= (const float*)d_in[15];
  const float* w_ih0 = (const float*)d_in[16];
  const float* w_hh0 = (const float*)d_in[17];
  const float* b_ih0 = (const float*)d_in[18];
  const float* b_hh0 = (const float*)d_in[19];
  const float* w_ih1 = (const float*)d_in[20];
  const float* w_hh1 = (const float*)d_in[21];
  const float* b_ih1 = (const float*)d_in[22];
  const float* b_hh1 = (const float*)d_in[23];
  const float* w_ih2 = (const float*)d_in[24];
  const float* w_hh2 = (const float*)d_in[25];
  const float* b_ih2 = (const float*)d_in[26];
  const float* b_hh2 = (const float*)d_in[27];
  const float* w_out = (const float*)d_in[28];
  const float* b_out = (const float*)d_in[29];
  float* dout = (float*)d_out;

  float* ws = (float*)d_ws;
  float* wp0   = ws; ws += (size_t)3 * cH * ISTR;   // padded w_ih0 (8.3 MB)
  float* wihfP = ws; ws += (size_t)3 * cH * WSTR;   // padded encoder w_ih fwd (5.1 MB)
  float* wihbP = ws; ws += (size_t)3 * cH * WSTR;   // padded encoder w_ih bwd (5.1 MB)
  float* hfA = ws; ws += cB * cH;  float* hfB = ws; ws += cB * cH;
  float* hbA = ws; ws += cB * cH;  float* hbB = ws; ws += cB * cH;
  float* h0A = ws; ws += cB * cH;  float* h0B = ws; ws += cB * cH;
  float* h1A = ws; ws += cB * cH;  float* h1B = ws; ws += cB * cH;
  float* h2A = ws; ws += cB * cH;  float* h2B = ws; ws += cB * cH;
  float* inp   = ws; ws += cB * ISTR;
  float* lgbuf = ws; ws += cB * cPF;
  unsigned* bar = (unsigned*)ws;   ws += 64;
  unsigned* cntE = bar +  0;
  unsigned* genE = bar + 16;
  unsigned* cntD = bar + 32;
  unsigned* genD = bar + 48;

  init_kernel<<<256, 256, 0, stream>>>(hfA, hbA, dout + (size_t)cB * cT * cPF, bar);
  pad_w0_kernel<<<512, 256, 0, stream>>>(w_ih0, wp0);
  pad_wih_kernel<<<512, 256, 0, stream>>>(wih_f, wihfP);
  pad_wih_kernel<<<512, 256, 0, stream>>>(wih_b, wihbP);

  enc_persist<<<NBLK, 512, 0, stream>>>(
      x,
      wihfP, whh_f, bih_f, bhh_f,
      wihbP, whh_b, bih_b, bhh_b,
      hfA, hfB, hbA, hbB, cntE, genE);

  dec_persist<<<NBLK, 512, 0, stream>>>(
      x, hfA, hbA,
      w_mu, b_mu, w_init, b_init,
      wp0, w_hh0, b_ih0, b_hh0,
      w_ih1, w_hh1, b_ih1, b_hh1,
      w_ih2, w_hh2, b_ih2, b_hh2,
      w_out, b_out,
      h0A, h0B, h1A, h1B, h2A, h2B,
      inp, lgbuf, dout, cntD, genD);
}

// Round 7
// 51214.252 us; speedup vs baseline: 3.5655x; 3.5655x over previous
//
#include <hip/hip_runtime.h>
#include <math.h>

namespace {

typedef unsigned long long u64;

constexpr int cH  = 1024;
constexpr int cZ  = 256;
constexpr int cB  = 64;
constexpr int cT  = 256;
constexpr int cR  = 389;
constexpr int cSC = 89;
constexpr int cPF = 300;
constexpr int WSTR = 400;               // padded encoder w_ih stride (floats) = 100 f4
constexpr float INV_S = 0.9999950000374997f;  // 1/sqrt(1+1e-5)

__device__ __forceinline__ void fma4(float4& a, const float4 x, const float4 w){
  a.x = fmaf(x.x, w.x, a.x);
  a.y = fmaf(x.y, w.y, a.y);
  a.z = fmaf(x.z, w.z, a.z);
  a.w = fmaf(x.w, w.w, a.w);
}
__device__ __forceinline__ float fold4(const float4 a){ return (a.x + a.y) + (a.z + a.w); }
__device__ __forceinline__ float4 z4(){ return make_float4(0.f, 0.f, 0.f, 0.f); }
__device__ __forceinline__ float sigm(float x){ return 1.f / (1.f + expf(-x)); }

// ---- guaranteed-coherent primitives (no inline-asm data movement) ----
__device__ __forceinline__ void cfence(){ asm volatile("" ::: "memory"); }
__device__ __forceinline__ u64 ld_u64(const u64* p){
  return __hip_atomic_load(p, __ATOMIC_RELAXED, __HIP_MEMORY_SCOPE_AGENT);
}
__device__ __forceinline__ float ld_scal(const float* p){
  return __hip_atomic_load(p, __ATOMIC_RELAXED, __HIP_MEMORY_SCOPE_AGENT);
}
__device__ __forceinline__ void st_scal(float* p, float v){
  __hip_atomic_store(p, v, __ATOMIC_RELAXED, __HIP_MEMORY_SCOPE_AGENT);
}

// ---- two-level group barrier; RELEASE arrival orders prior agent stores ----
// layout per domain (uint slots): sub s at [s*16], root at [nsub*16], gen at [nsub*16+16]
__device__ __forceinline__ void gbarN(unsigned* base, int sub, unsigned subCnt,
                                      int nsub, unsigned rootCnt){
  __syncthreads();                       // compiler drains vmcnt before s_barrier
  if (threadIdx.x == 0){
    cfence();
    unsigned* root = base + nsub * 16;
    unsigned* gen  = base + nsub * 16 + 16;
    const unsigned g = __hip_atomic_load(gen, __ATOMIC_RELAXED, __HIP_MEMORY_SCOPE_AGENT);
    const unsigned a = __hip_atomic_fetch_add(base + sub * 16, 1u,
                         __ATOMIC_RELEASE, __HIP_MEMORY_SCOPE_AGENT);
    bool flip = false;
    if (a == subCnt - 1u){
      const unsigned r = __hip_atomic_fetch_add(root, 1u,
                           __ATOMIC_RELEASE, __HIP_MEMORY_SCOPE_AGENT);
      if (r == rootCnt - 1u){
        for (int t = 0; t < nsub; ++t)
          __hip_atomic_store(base + t * 16, 0u, __ATOMIC_RELAXED, __HIP_MEMORY_SCOPE_AGENT);
        __hip_atomic_store(root, 0u, __ATOMIC_RELAXED, __HIP_MEMORY_SCOPE_AGENT);
        __hip_atomic_store(gen, g + 1u, __ATOMIC_RELEASE, __HIP_MEMORY_SCOPE_AGENT);
        flip = true;
      }
    }
    if (!flip){
      while (__hip_atomic_load(gen, __ATOMIC_RELAXED, __HIP_MEMORY_SCOPE_AGENT) == g)
        __builtin_amdgcn_s_sleep(1);
    }
    cfence();
  }
  __syncthreads();
}

// ---------------------------------------------------------------- prep kernels
__global__ __launch_bounds__(256) void init_kernel(float* hf0, float* hb0, float* dout_tail,
                                                   unsigned* barE, unsigned* barD){
  const int idx = blockIdx.x * 256 + threadIdx.x;
  const int stride = gridDim.x * 256;
  for (int i = idx; i < cB * cH; i += stride){ hf0[i] = 0.f; hb0[i] = 0.f; }
  for (int i = idx; i < 2 * cB * cZ; i += stride) dout_tail[i] = 0.f;
  for (int i = idx; i < 2048; i += stride) barE[i] = 0u;
  for (int i = idx; i < 512;  i += stride) barD[i] = 0u;
}

__global__ __launch_bounds__(256) void pad_wih_kernel(const float* __restrict__ w,
                                                      float* __restrict__ wp){
  const int idx = blockIdx.x * 256 + threadIdx.x;
  const int stride = gridDim.x * 256;
  const int n = 3 * cH * WSTR;
  for (int i = idx; i < n; i += stride){
    const int r = i / WSTR, c = i - r * WSTR;
    wp[i] = (c < cR) ? w[(size_t)r * cR + c] : 0.f;
  }
}

__global__ __launch_bounds__(256) void pad_wsc_kernel(const float* __restrict__ w_ih0,
                                                      float* __restrict__ wsc){
  const int idx = blockIdx.x * 256 + threadIdx.x;
  const int stride = gridDim.x * 256;
  const int n = 3 * cH * 96;
  for (int i = idx; i < n; i += stride){
    const int r = i / 96, c = i - r * 96;
    wsc[i] = (c < cSC) ? w_ih0[(size_t)r * 645 + 300 + c] : 0.f;
  }
}

// ---------------------------------------------------------------- encoder (persistent)
// 256 blocks, XCD-swizzled: xcd=bid&7, slot=bid>>3; dir=slot>>4, sub16=slot&15;
// kblk = xcd*8 + (sub16>>1) (16 k-rows), bhalf = sub16&1 (32 batches).
// tid 512: seg8=tid>>6 -> dseg=seg8&3, khalf=seg8>>2; lane: tx=lane&7, ty=lane>>3.
__global__ __launch_bounds__(512, 2) void enc_persist(
    const float* __restrict__ x,
    const float* __restrict__ wihPf, const float* __restrict__ whh_f,
    const float* __restrict__ bih_f, const float* __restrict__ bhh_f,
    const float* __restrict__ wihPb, const float* __restrict__ whh_b,
    const float* __restrict__ bih_b, const float* __restrict__ bhh_b,
    float* __restrict__ hfA, float* __restrict__ hfB,
    float* __restrict__ hbA, float* __restrict__ hbB,
    unsigned* __restrict__ barE)
{
  const int bid   = blockIdx.x;
  const int xcd   = bid & 7;
  const int slot  = bid >> 3;
  const int dir   = slot >> 4;
  const int sub16 = slot & 15;
  const int kblk  = xcd * 8 + (sub16 >> 1);
  const int bhalf = sub16 & 1;
  unsigned* bar   = barE + (dir * 2 + bhalf) * 512;

  const float* wih = dir ? wihPb : wihPf;
  const float* whh = dir ? whh_b : whh_f;
  const float* bih = dir ? bih_b : bih_f;
  const float* bhh = dir ? bhh_b : bhh_f;
  float* bufA = dir ? hbA : hfA;
  float* bufB = dir ? hbB : hfB;

  const int tid   = threadIdx.x;
  const int seg8  = tid >> 6;
  const int dseg  = seg8 & 3;
  const int khalf = seg8 >> 2;
  const int lane  = tid & 63;
  const int tx    = lane & 7;
  const int ty    = lane >> 3;
  const int k0    = kblk * 16;
  const int bbase = bhalf * 32;
  const int kloc  = khalf * 8 + ty;      // 0..15
  const int k     = k0 + kloc;

  __shared__ float part[4][4][16][33];            // 33.8 KB
  __shared__ alignas(16) float sh[32 * 516];      // 66 KB: 32 rows x 129 f4

  const float4* w0i = (const float4*)wih + (size_t)k * 100;
  const float4* w1i = (const float4*)wih + (size_t)(cH + k) * 100;
  const float4* w2i = (const float4*)wih + (size_t)(2*cH + k) * 100;
  const float4* w0h = (const float4*)whh + (size_t)k * 256;
  const float4* w1h = (const float4*)whh + (size_t)(cH + k) * 256;
  const float4* w2h = (const float4*)whh + (size_t)(2*cH + k) * 256;
  float4* sh4 = (float4*)sh;

  auto stageE = [&](const float* hin, int p){
    const u64* s8 = (const u64*)hin;
    u64* d8 = (u64*)sh;
    u64 tmp[16];
    #pragma unroll
    for (int i = 0; i < 16; ++i){
      const int e = i * 512 + tid;
      tmp[i] = ld_u64(s8 + (size_t)(bbase + (e >> 8)) * 512 + p * 256 + (e & 255));
    }
    #pragma unroll
    for (int i = 0; i < 16; ++i){
      const int e = i * 512 + tid;
      d8[(e >> 8) * 258 + (e & 255)] = tmp[i];
    }
  };

  for (int t = 0; t < cT; ++t){
    const float* hin = (t & 1) ? bufB : bufA;
    float*      hout = (t & 1) ? bufA : bufB;
    const int tt = dir ? (cT - 1 - t) : t;

    float4 R[4], Z[4], NI[4], NH[4];
    #pragma unroll
    for (int jj = 0; jj < 4; ++jj){ R[jj]=z4(); Z[jj]=z4(); NI[jj]=z4(); NH[jj]=z4(); }

    // ---- phase 1: x @ w_ih^T (padded f4 weights, clamped scalar x reads)
    {
      const float* xb[4];
      #pragma unroll
      for (int jj = 0; jj < 4; ++jj)
        xb[jj] = x + ((size_t)tt * cB + bbase + tx + 8*jj) * cR;
      const int c0 = dseg * 25;
      const int cEnd = c0 + 25;
      const int cSafe = (cEnd < 97) ? cEnd : 97;
      for (int c = c0; c < cSafe; ++c){
        const float4 w0v = w0i[c], w1v = w1i[c], w2v = w2i[c];
        const int d = 4 * c;
        #pragma unroll
        for (int jj = 0; jj < 4; ++jj){
          const float* xr = xb[jj];
          const float4 a = make_float4(xr[d], xr[d+1], xr[d+2], xr[d+3]);
          fma4(R[jj], a, w0v); fma4(Z[jj], a, w1v); fma4(NI[jj], a, w2v);
        }
      }
      for (int c = cSafe; c < cEnd; ++c){
        const float4 w0v = w0i[c], w1v = w1i[c], w2v = w2i[c];
        const int d = 4 * c;
        #pragma unroll
        for (int jj = 0; jj < 4; ++jj){
          const float* xr = xb[jj];
          const float4 a = make_float4(
              (d   < cR) ? xr[d]   : 0.f, (d+1 < cR) ? xr[d+1] : 0.f,
              (d+2 < cR) ? xr[d+2] : 0.f, (d+3 < cR) ? xr[d+3] : 0.f);
          fma4(R[jj], a, w0v); fma4(Z[jj], a, w1v); fma4(NI[jj], a, w2v);
        }
      }
    }

    // ---- phase 2: h @ w_hh^T, two staged halves
    #pragma unroll 1
    for (int p = 0; p < 2; ++p){
      stageE(hin, p);
      __syncthreads();
      {
        const float4* wp0 = w0h + p * 128;
        const float4* wp1 = w1h + p * 128;
        const float4* wp2 = w2h + p * 128;
        #pragma unroll 4
        for (int c = 0; c < 32; ++c){
          const int cc = dseg * 32 + c;
          const float4 w0v = wp0[cc], w1v = wp1[cc], w2v = wp2[cc];
          #pragma unroll
          for (int jj = 0; jj < 4; ++jj){
            const float4 a = sh4[(tx + 8*jj)*129 + cc];
            fma4(R[jj], a, w0v); fma4(Z[jj], a, w1v); fma4(NH[jj], a, w2v);
          }
        }
      }
      __syncthreads();
    }

    #pragma unroll
    for (int jj = 0; jj < 4; ++jj){
      const int b = tx + 8*jj;
      part[dseg][0][kloc][b] = fold4(R[jj]);
      part[dseg][1][kloc][b] = fold4(Z[jj]);
      part[dseg][2][kloc][b] = fold4(NI[jj]);
      part[dseg][3][kloc][b] = fold4(NH[jj]);
    }
    __syncthreads();
    {
      const int row = tid >> 5, bb = tid & 31;   // 16 x 32 = 512 outputs
      float rs=0.f, zs=0.f, nis=0.f, nhs=0.f;
      #pragma unroll
      for (int s = 0; s < 4; ++s){
        rs += part[s][0][row][bb]; zs += part[s][1][row][bb];
        nis += part[s][2][row][bb]; nhs += part[s][3][row][bb];
      }
      const int kk = k0 + row, gb = bbase + bb;
      const float r  = sigm(rs + bih[kk] + bhh[kk]);
      const float zg = sigm(zs + bih[cH + kk] + bhh[cH + kk]);
      const float nn = tanhf(nis + bih[2*cH + kk] + r * (nhs + bhh[2*cH + kk]));
      const float hp = ld_scal(&hin[(size_t)gb * cH + kk]);
      st_scal(&hout[(size_t)gb * cH + kk], (1.f - zg) * nn + zg * hp);
    }
    gbarN(bar, kblk >> 3, 8u, 8, 8u);
  }
}

// ---------------------------------------------------------------- decoder (persistent)
// 256 blocks, XCD-swizzled: xcd=bid&7, slot=bid>>3; kq = xcd*16 + (slot>>1) (8 k-rows),
// bh = slot&1 (32 batches).  One 256-block barrier domain (16 subs x 16).
// tid 512: seg=tid>>6 (d-split 8); lane: ty=lane>>3 (k-row), tx=lane&7; b = tx + 8*jj.
__global__ __launch_bounds__(512, 2) void dec_persist(
    const float* __restrict__ x,
    const float* __restrict__ hfA, const float* __restrict__ hbA,
    const float* __restrict__ w_mu, const float* __restrict__ b_mu,
    const float* __restrict__ w_init, const float* __restrict__ b_init,
    const float* __restrict__ w_ih0,
    const float* __restrict__ wsc,   const float* __restrict__ w_hh0,
    const float* __restrict__ b_ih0, const float* __restrict__ b_hh0,
    const float* __restrict__ w_ih1, const float* __restrict__ w_hh1,
    const float* __restrict__ b_ih1, const float* __restrict__ b_hh1,
    const float* __restrict__ w_ih2, const float* __restrict__ w_hh2,
    const float* __restrict__ b_ih2, const float* __restrict__ b_hh2,
    const float* __restrict__ w_out, const float* __restrict__ b_out,
    float* __restrict__ h0A, float* __restrict__ h0B,
    float* __restrict__ h1A, float* __restrict__ h1B,
    float* __restrict__ h2A, float* __restrict__ h2B,
    float* __restrict__ gi0z, float* __restrict__ zbuf,
    float* __restrict__ amg,  float* __restrict__ scg,
    float* __restrict__ dout,
    unsigned* __restrict__ barD)
{
  const int bid  = blockIdx.x;
  const int xcd  = bid & 7;
  const int slot = bid >> 3;
  const int kq   = xcd * 16 + (slot >> 1);
  const int bh   = slot & 1;
  const int kbase = kq * 8;
  const int bbase = bh * 32;
  const int tid = threadIdx.x;

  const int seg  = tid >> 6;
  const int lane = tid & 63;
  const int tx   = lane & 7;
  const int ty   = lane >> 3;
  const int k    = kbase + ty;

  __shared__ float part[8][4][8][33];              // 33.8 KB
  __shared__ alignas(16) float stg[16 * 1028];     // 65.8 KB (16 rows x 257 f4)
  __shared__ alignas(16) float scs[32 * 100];      // 12.8 KB
  __shared__ float ams[32];
  __shared__ alignas(16) float hb2[cH];            // 4 KB (fold)
  __shared__ float lg[cPF];
  __shared__ float gmax[3], glse[3], wbest[8];
  __shared__ int   wbidx[8];

  float4* stg4 = (float4*)stg;

  #define GBD gbarN(barD, bid >> 4, 16u, 16, 16u)

  auto stageH = [&](const float* src, int gb0){
    const u64* s8 = (const u64*)src;
    u64* d8 = (u64*)stg;
    u64 tmp[16];
    #pragma unroll
    for (int i = 0; i < 16; ++i){
      const int e = i * 512 + tid;
      tmp[i] = ld_u64(s8 + (size_t)(gb0 + (e >> 9)) * 512 + (e & 511));
    }
    #pragma unroll
    for (int i = 0; i < 16; ++i){
      const int e = i * 512 + tid;
      d8[(e >> 9) * 514 + (e & 511)] = tmp[i];
    }
  };

  // accumulate stage rows tx and tx+8 over cols seg*32..+32
  auto accH = [&](const float4* w0, const float4* w1, const float4* w2,
                  float4& A0, float4& A1, float4& B0, float4& B1,
                  float4& C0, float4& C1){
    #pragma unroll 4
    for (int c = 0; c < 32; ++c){
      const int cc = seg * 32 + c;
      const float4 w0v = w0[cc], w1v = w1[cc], w2v = w2[cc];
      const float4 aA = stg4[tx * 257 + cc];
      const float4 aB = stg4[(tx + 8) * 257 + cc];
      fma4(A0, aA, w0v); fma4(B0, aA, w1v); fma4(C0, aA, w2v);
      fma4(A1, aB, w0v); fma4(B1, aB, w1v); fma4(C1, aB, w2v);
    }
  };

  auto reduce_store = [&](const float* bi, const float* bhv,
                          const float* hprev, float* hout){
    __syncthreads();
    if (tid < 256){
      const int row = tid >> 5, b = tid & 31;
      float rs=0.f, zs=0.f, nis=0.f, nhs=0.f;
      #pragma unroll
      for (int s = 0; s < 8; ++s){
        rs += part[s][0][row][b]; zs += part[s][1][row][b];
        nis += part[s][2][row][b]; nhs += part[s][3][row][b];
      }
      const int kk = kbase + row, gb = bbase + b;
      const float r  = sigm(rs + bi[kk] + bhv[kk]);
      const float zg = sigm(zs + bi[cH + kk] + bhv[cH + kk]);
      const float nn = tanhf(nis + bi[2*cH + kk] + r * (nhs + bhv[2*cH + kk]));
      const float hp = ld_scal(&hprev[(size_t)gb * cH + kk]);
      st_scal(&hout[(size_t)gb * cH + kk], (1.f - zg) * nn + zg * hp);
    }
  };

  // ================= prologue =================
  if (bid < cB){
    const int b = bid;
    float4* hl4 = (float4*)stg;
    hl4[tid] = (tid < 256) ? ((const float4*)hfA)[(size_t)b * 256 + tid]
                           : ((const float4*)hbA)[(size_t)b * 256 + (tid - 256)];
    __syncthreads();
    if (tid < 256){
      const float4* wr = (const float4*)w_mu + (size_t)tid * 512;
      float4 s = z4();
      #pragma unroll 4
      for (int c = 0; c < 512; ++c) fma4(s, hl4[c], wr[c]);
      st_scal(&zbuf[(size_t)b * cZ + tid], b_mu[tid] + fold4(s) * INV_S);
    }
    if (tid == 0) st_scal(&amg[b], 299.f);
    if (tid < 96) st_scal(&scg[(size_t)b * 96 + tid], (tid == 88) ? 1.f : 0.f);
  }
  GBD;
  {
    // stage z for this block's 32 batches into LDS (row stride 260 floats = 130 u64)
    float* zl = stg;
    {
      u64 tmp[8];
      const u64* zb8 = (const u64*)zbuf;
      u64* zl8 = (u64*)stg;
      #pragma unroll
      for (int q = 0; q < 8; ++q){
        const int e = q * 512 + tid;
        tmp[q] = ld_u64(zb8 + (size_t)(bbase + (e >> 7)) * 128 + (e & 127));
      }
      #pragma unroll
      for (int q = 0; q < 8; ++q){
        const int e = q * 512 + tid;
        zl8[(e >> 7) * 130 + (e & 127)] = tmp[q];
      }
    }
    __syncthreads();
    for (int e = tid; e < 768; e += 512){   // gi0z slice: 3 gates x 8 rows x 32 batches
      const int g = e >> 8, kr = (e >> 5) & 7, b = e & 31;
      const float* zr = zl + b * 260;
      const float* wrow = w_ih0 + (size_t)(g * cH + kbase + kr) * 645 + 389;
      float s = 0.f;
      #pragma unroll 4
      for (int d = 0; d < cZ; ++d) s = fmaf(zr[d], wrow[d], s);
      st_scal(&gi0z[(size_t)(g * cH + kbase + kr) * 64 + bbase + b], s);
    }
    if (tid < 256){                          // hinit slice: 8 rows x 32 batches
      const int kr = tid >> 5, b = tid & 31;
      const float4* zr4 = (const float4*)(zl + b * 260);
      const float4* wr4 = (const float4*)w_init + (size_t)(kbase + kr) * 64;
      float4 s = z4();
      #pragma unroll 4
      for (int d = 0; d < 64; ++d) fma4(s, zr4[d], wr4[d]);
      st_scal(&h0A[(size_t)(bbase + b) * cH + kbase + kr],
              tanhf(b_init[kbase + kr] + fold4(s)));
    }
  }
  GBD;

  // ================= main loop =================
  for (int j = 0; j < cT; ++j){
    const int par = j & 1;
    const float* h0p = par ? h0B : h0A;  float* h0n = par ? h0A : h0B;
    const float* h1p = par ? h1B : h1A;  float* h1n = par ? h1A : h1B;
    const float* h2p = par ? h2B : h2A;  float* h2n = par ? h2A : h2B;

    // ---- phase A: layer 0 (one-hot gather + sc GEMM + precomputed z-part + hh GEMM)
    {
      {  // stage scores (96 floats/row = 48 u64) + argmax indices
        u64 tmp[3];
        const u64* sg8 = (const u64*)scg;
        u64* sc8 = (u64*)scs;
        #pragma unroll
        for (int i = 0; i < 3; ++i){
          const int e = i * 512 + tid;           // 0..1535
          const int row = e / 48, col = e - row * 48;
          tmp[i] = ld_u64(sg8 + (size_t)(bbase + row) * 48 + col);
        }
        #pragma unroll
        for (int i = 0; i < 3; ++i){
          const int e = i * 512 + tid;
          const int row = e / 48, col = e - row * 48;
          sc8[row * 50 + col] = tmp[i];
        }
        if (tid < 32) ams[tid] = ld_scal(&amg[bbase + tid]);
      }
      __syncthreads();

      float4 R[4], Z[4], NI[4], NH[4];
      float sR[4], sZ[4], sNI[4];
      #pragma unroll
      for (int jj = 0; jj < 4; ++jj){
        R[jj]=z4(); Z[jj]=z4(); NI[jj]=z4(); NH[jj]=z4();
        sR[jj]=0.f; sZ[jj]=0.f; sNI[jj]=0.f;
      }
      {  // score GEMM: cols seg*3..+3 of 24 f4
        const float4* ws0 = (const float4*)wsc + (size_t)k * 24;
        const float4* ws1 = (const float4*)wsc + (size_t)(cH + k) * 24;
        const float4* ws2 = (const float4*)wsc + (size_t)(2*cH + k) * 24;
        const float4* sc4 = (const float4*)scs;
        #pragma unroll
        for (int c = 0; c < 3; ++c){
          const int cc = seg * 3 + c;
          const float4 w0v = ws0[cc], w1v = ws1[cc], w2v = ws2[cc];
          #pragma unroll
          for (int jj = 0; jj < 4; ++jj){
            const float4 a = sc4[(tx + 8*jj) * 25 + cc];
            fma4(R[jj], a, w0v); fma4(Z[jj], a, w1v); fma4(NI[jj], a, w2v);
          }
        }
      }
      if (seg == 0){  // one-hot gather + precomputed z-part (once per (k,b))
        #pragma unroll
        for (int jj = 0; jj < 4; ++jj){
          const int b = tx + 8*jj, gb = bbase + b;
          const int am = (int)ams[b];
          sR[jj]  = w_ih0[(size_t)k * 645 + am]
                  + ld_scal(&gi0z[(size_t)k * 64 + gb]);
          sZ[jj]  = w_ih0[(size_t)(cH + k) * 645 + am]
                  + ld_scal(&gi0z[(size_t)(cH + k) * 64 + gb]);
          sNI[jj] = w_ih0[(size_t)(2*cH + k) * 645 + am]
                  + ld_scal(&gi0z[(size_t)(2*cH + k) * 64 + gb]);
        }
      }
      const float4* wh0 = (const float4*)w_hh0 + (size_t)k * 256;
      const float4* wh1 = (const float4*)w_hh0 + (size_t)(cH + k) * 256;
      const float4* wh2 = (const float4*)w_hh0 + (size_t)(2*cH + k) * 256;
      __syncthreads();
      stageH(h0p, bbase);      __syncthreads();
      accH(wh0, wh1, wh2, R[0], R[1], Z[0], Z[1], NH[0], NH[1]);
      __syncthreads();
      stageH(h0p, bbase + 16); __syncthreads();
      accH(wh0, wh1, wh2, R[2], R[3], Z[2], Z[3], NH[2], NH[3]);
      #pragma unroll
      for (int jj = 0; jj < 4; ++jj){
        const int b = tx + 8*jj;
        part[seg][0][ty][b] = fold4(R[jj]) + sR[jj];
        part[seg][1][ty][b] = fold4(Z[jj]) + sZ[jj];
        part[seg][2][ty][b] = fold4(NI[jj]) + sNI[jj];
        part[seg][3][ty][b] = fold4(NH[jj]);
      }
      reduce_store(b_ih0, b_hh0, h0p, h0n);
    }
    GBD;

    // ---- phases B, C: layers 1, 2
    #pragma unroll 1
    for (int L = 0; L < 2; ++L){
      const float* inG = (L == 0) ? h0n : h1n;
      const float* pvG = (L == 0) ? (j == 0 ? h0n : h1p) : (j == 0 ? h1n : h2p);
      const float* wih = (L == 0) ? w_ih1 : w_ih2;
      const float* whh = (L == 0) ? w_hh1 : w_hh2;
      const float* bi  = (L == 0) ? b_ih1 : b_ih2;
      const float* bhv = (L == 0) ? b_hh1 : b_hh2;
      float* outG      = (L == 0) ? h1n : h2n;

      float4 R[4], Z[4], NI[4], NH[4];
      #pragma unroll
      for (int jj = 0; jj < 4; ++jj){ R[jj]=z4(); Z[jj]=z4(); NI[jj]=z4(); NH[jj]=z4(); }
      const float4* wi0 = (const float4*)wih + (size_t)k * 256;
      const float4* wi1 = (const float4*)wih + (size_t)(cH + k) * 256;
      const float4* wi2 = (const float4*)wih + (size_t)(2*cH + k) * 256;
      const float4* wh0 = (const float4*)whh + (size_t)k * 256;
      const float4* wh1 = (const float4*)whh + (size_t)(cH + k) * 256;
      const float4* wh2 = (const float4*)whh + (size_t)(2*cH + k) * 256;

      stageH(inG, bbase);      __syncthreads();
      accH(wi0, wi1, wi2, R[0], R[1], Z[0], Z[1], NI[0], NI[1]);
      __syncthreads();
      stageH(inG, bbase + 16); __syncthreads();
      accH(wi0, wi1, wi2, R[2], R[3], Z[2], Z[3], NI[2], NI[3]);
      __syncthreads();
      stageH(pvG, bbase);      __syncthreads();
      accH(wh0, wh1, wh2, R[0], R[1], Z[0], Z[1], NH[0], NH[1]);
      __syncthreads();
      stageH(pvG, bbase + 16); __syncthreads();
      accH(wh0, wh1, wh2, R[2], R[3], Z[2], Z[3], NH[2], NH[3]);
      #pragma unroll
      for (int jj = 0; jj < 4; ++jj){
        const int b = tx + 8*jj;
        part[seg][0][ty][b] = fold4(R[jj]);
        part[seg][1][ty][b] = fold4(Z[jj]);
        part[seg][2][ty][b] = fold4(NI[jj]);
        part[seg][3][ty][b] = fold4(NH[jj]);
      }
      reduce_store(bi, bhv, pvG, outG);
      GBD;
    }

    // ---- phase FOLD: blocks 0..63 — logits + log_softmax + argmax + next-step am/sc
    if (bid < cB){
      const int b = bid;
      ((u64*)hb2)[tid] = ld_u64((const u64*)h2n + (size_t)b * 512 + tid);
      __syncthreads();
      for (int p = tid; p < cPF; p += 512){
        const float4* wr = (const float4*)w_out + (size_t)p * 256;
        const float4* hv = (const float4*)hb2;
        float4 s = z4();
        #pragma unroll 4
        for (int c = 0; c < 256; ++c) fma4(s, hv[c], wr[c]);
        lg[p] = b_out[p] + fold4(s);
      }
      __syncthreads();
      const int w = tid >> 6, l = tid & 63;
      if (w < 3){
        float m = -INFINITY;
        for (int p = w*100 + l; p < w*100 + 100; p += 64) m = fmaxf(m, lg[p]);
        #pragma unroll
        for (int off = 32; off > 0; off >>= 1) m = fmaxf(m, __shfl_xor(m, off));
        float s = 0.f;
        for (int p = w*100 + l; p < w*100 + 100; p += 64) s += expf(lg[p] - m);
        #pragma unroll
        for (int off = 32; off > 0; off >>= 1) s += __shfl_xor(s, off);
        if (l == 0){ gmax[w] = m; glse[w] = logf(s); }
      }
      __syncthreads();
      float best = -INFINITY; int bidx = 0x7fffffff;
      for (int p = tid; p < cPF; p += 512){
        const int g3 = (p >= 200) ? 2 : ((p >= 100) ? 1 : 0);
        const float o = lg[p] - gmax[g3] - glse[g3];
        dout[((size_t)b * cT + j) * cPF + p] = o;
        if (o > best || (o == best && p < bidx)){ best = o; bidx = p; }
      }
      #pragma unroll
      for (int off = 32; off > 0; off >>= 1){
        const float ob = __shfl_xor(best, off);
        const int   oi = __shfl_xor(bidx, off);
        if (ob > best || (ob == best && oi < bidx)){ best = ob; bidx = oi; }
      }
      if (l == 0){ wbest[w] = best; wbidx[w] = bidx; }
      __syncthreads();
      if (tid == 0){
        float bb = wbest[0]; int bi = wbidx[0];
        #pragma unroll
        for (int q = 1; q < 8; ++q)
          if (wbest[q] > bb || (wbest[q] == bb && wbidx[q] < bi)){ bb = wbest[q]; bi = wbidx[q]; }
        st_scal(&amg[b], (float)bi);
      }
      if (tid < 96)
        st_scal(&scg[(size_t)b * 96 + tid],
                (tid < cSC) ? x[((size_t)j * cB + b) * cR + tid] : 0.f);
    }
    GBD;
  }
  #undef GBD
}

} // namespace

// ---------------------------------------------------------------- host
extern "C" void kernel_launch(void* const* d_in, const int* in_sizes, int n_in,
                              void* d_out, int out_size, void* d_ws, size_t ws_size,
                              hipStream_t stream)
{
  const float* x     = (const float*)d_in[0];
  const float* wih_f = (const float*)d_in[2];
  const float* whh_f = (const float*)d_in[3];
  const float* bih_f = (const float*)d_in[4];
  const float* bhh_f = (const float*)d_in[5];
  const float* wih_b = (const float*)d_in[6];
  const float* whh_b = (const float*)d_in[7];
  const float* bih_b = (const float*)d_in[8];
  const float* bhh_b = (const float*)d_in[9];
  const float* w_mu  = (const float*)d_in[10];
  const float* b_mu  = (const float*)d_in[11];
  const float* w_init= (const float*)d_in[14];
  const float* b_init= (const float*)d_in[15];
  const float* w_ih0 = (const float*)d_in[16];
  const float* w_hh0 = (const float*)d_in[17];
  const float* b_ih0 = (const float*)d_in[18];
  const float* b_hh0 = (const float*)d_in[19];
  const float* w_ih1 = (const float*)d_in[20];
  const float* w_hh1 = (const float*)d_in[21];
  const float* b_ih1 = (const float*)d_in[22];
  const float* b_hh1 = (const float*)d_in[23];
  const float* w_ih2 = (const float*)d_in[24];
  const float* w_hh2 = (const float*)d_in[25];
  const float* b_ih2 = (const float*)d_in[26];
  const float* b_hh2 = (const float*)d_in[27];
  const float* w_out = (const float*)d_in[28];
  const float* b_out = (const float*)d_in[29];
  float* dout = (float*)d_out;

  float* ws = (float*)d_ws;
  float* wihfP = ws; ws += (size_t)3 * cH * WSTR;     // 4.9 MB
  float* wihbP = ws; ws += (size_t)3 * cH * WSTR;     // 4.9 MB
  float* wsc   = ws; ws += (size_t)3 * cH * 96;       // 1.2 MB
  float* gi0z  = ws; ws += (size_t)3 * cH * 64;       // 0.8 MB
  float* hfA = ws; ws += cB * cH;  float* hfB = ws; ws += cB * cH;
  float* hbA = ws; ws += cB * cH;  float* hbB = ws; ws += cB * cH;
  float* h0A = ws; ws += cB * cH;  float* h0B = ws; ws += cB * cH;
  float* h1A = ws; ws += cB * cH;  float* h1B = ws; ws += cB * cH;
  float* h2A = ws; ws += cB * cH;  float* h2B = ws; ws += cB * cH;
  float* zbuf = ws; ws += cB * cZ;
  float* scg  = ws; ws += cB * 96;
  float* amg  = ws; ws += cB;
  ws = (float*)(((uintptr_t)ws + 255) & ~(uintptr_t)255);
  unsigned* barE = (unsigned*)ws;  ws += 2048;  // 4 domains x 512
  unsigned* barD = (unsigned*)ws;  ws += 512;   // 1 domain

  init_kernel<<<256, 256, 0, stream>>>(hfA, hbA, dout + (size_t)cB * cT * cPF, barE, barD);
  pad_wih_kernel<<<512, 256, 0, stream>>>(wih_f, wihfP);
  pad_wih_kernel<<<512, 256, 0, stream>>>(wih_b, wihbP);
  pad_wsc_kernel<<<512, 256, 0, stream>>>(w_ih0, wsc);

  enc_persist<<<256, 512, 0, stream>>>(
      x,
      wihfP, whh_f, bih_f, bhh_f,
      wihbP, whh_b, bih_b, bhh_b,
      hfA, hfB, hbA, hbB, barE);

  dec_persist<<<256, 512, 0, stream>>>(
      x, hfA, hbA,
      w_mu, b_mu, w_init, b_init,
      w_ih0, wsc, w_hh0, b_ih0, b_hh0,
      w_ih1, w_hh1, b_ih1, b_hh1,
      w_ih2, w_hh2, b_ih2, b_hh2,
      w_out, b_out,
      h0A, h0B, h1A, h1B, h2A, h2B,
      gi0z, zbuf, amg, scg, dout, barD);
}